// Round 13
// baseline (374.005 us; speedup 1.0000x reference)
//
#include <hip/hip_runtime.h>

// Problem constants (from setup_inputs)
#define ND0 90112
#define ND1 8192
#define NDT (ND0 + ND1)         // 98304 combined dst space
#define NE0 1351680
#define NE1 81920
#define NET (NE0 + NE1)
#define F_IN 128
#define HID 256
#define F_OUT 128
#define BCAP 64                 // per-dst bucket capacity; P(deg>=64) ~ 1e-56
#define WT_BLOCKS 512           // prep_k blocks doing weight transpose

typedef __attribute__((ext_vector_type(8))) short short8;
typedef __attribute__((ext_vector_type(4))) float f32x4;

__device__ inline ushort f2bf(float f) {
    unsigned u = __float_as_uint(f);
    return (ushort)((u + 0x7fffu + ((u >> 16) & 1u)) >> 16);
}
__device__ inline float bf2f(ushort h) {
    return __uint_as_float(((unsigned)h) << 16);
}

// ------------------------------------------------------------------
// prep: weight transpose+convert (blocks [0,512)) + one-kernel bucket
// CSR build (blocks [512, 512+5600)). Row d's srcs: bkt[d*BCAP .. +cnt[d]).
// ------------------------------------------------------------------
__global__ void prep_k(const float* __restrict__ Wl0, const float* __restrict__ Wr0,
                       const float* __restrict__ Wl1, const float* __restrict__ Wr1,
                       ushort* __restrict__ Bt0, ushort* __restrict__ Bt1,
                       const int* __restrict__ esrc0, const int* __restrict__ edst0,
                       const int* __restrict__ esrc1, const int* __restrict__ edst1,
                       const int* __restrict__ nid, int* __restrict__ cnt,
                       int* __restrict__ bkt) {
    if (blockIdx.x < WT_BLOCKS) {
        int idx = blockIdx.x * 256 + threadIdx.x;
        constexpr int N0 = HID * 2 * F_IN;  // 65536
        if (idx < N0) {
            int K2 = 2 * F_IN;
            int n = idx / K2, k = idx - n * K2;
            float v = (k < F_IN) ? Wl0[(size_t)k * HID + n]
                                 : Wr0[(size_t)(k - F_IN) * HID + n];
            Bt0[idx] = f2bf(v);
        } else {
            int j = idx - N0;  // F_OUT * 2 * HID = 65536
            int K2 = 2 * HID;
            int n = j / K2, k = j - n * K2;
            float v = (k < HID) ? Wl1[(size_t)k * F_OUT + n]
                                : Wr1[(size_t)(k - HID) * F_OUT + n];
            Bt1[j] = f2bf(v);
        }
    } else {
        int e = (blockIdx.x - WT_BLOCKS) * 256 + threadIdx.x;
        if (e >= NET) return;
        int d, s;
        if (e < NE0) {
            d = edst0[e];
            s = nid[esrc0[e]];
        } else {
            int e1 = e - NE0;
            d = ND0 + edst1[e1];
            s = esrc1[e1];
        }
        int pos = atomicAdd(&cnt[d], 1);
        if (pos < BCAP) bkt[(size_t)d * BCAP + pos] = s;
    }
}

// ------------------------------------------------------------------
// FUSED layer-1: aggregate (mean) + x_dst gather -> LDS A-tile -> MFMA GEMM
//   h[64 rows][256] = relu([mean | x_dst] @ Bt0^T + bias)
// BM=64: 1408 blocks x 512 threads (8 waves).
// Lane map (R10): u = t&3 -> 16B chunk within 64B window (coalesced).
// R13: copy-free A/B ping-pong in the edge loop — consuming A waits only
// vmcnt for A while B's 8 loads stay in flight (R11's v=w copy forced
// vmcnt(0) each iter, which is why it nulled). FP sum order identical.
// ------------------------------------------------------------------
__global__ __launch_bounds__(512, 4) void fused1_k(
    const float* __restrict__ X, const int* __restrict__ bkt,
    const int* __restrict__ cnt, const int* __restrict__ nid,
    const ushort* __restrict__ Bt, const float* __restrict__ bias,
    ushort* __restrict__ C) {
    __shared__ ushort As[64][264];  // [row][mean(0..127) | xdst(128..255)], +8 pad
    __shared__ ushort Bs[64][72];
    __shared__ int s_num[64];

    int t = threadIdx.x;
    int row0 = blockIdx.x * 64;

    if (t < 64) s_num[t] = cnt[row0 + t];
    __syncthreads();

    // ---------- phase 1a: x_dst gather (8 threads/row, 16 cols each) ----------
    {
        int row = t >> 3, q = t & 7;
        int gr = nid[row0 + row];
        const float* gp = &X[(size_t)gr * F_IN + q * 16];
#pragma unroll
        for (int i = 0; i < 2; ++i) {
            float4 v0 = *(const float4*)(gp + i * 8);
            float4 v1 = *(const float4*)(gp + i * 8 + 4);
            short8 o;
            o[0] = (short)f2bf(v0.x); o[1] = (short)f2bf(v0.y);
            o[2] = (short)f2bf(v0.z); o[3] = (short)f2bf(v0.w);
            o[4] = (short)f2bf(v1.x); o[5] = (short)f2bf(v1.y);
            o[6] = (short)f2bf(v1.z); o[7] = (short)f2bf(v1.w);
            *(short8*)&As[row][F_IN + q * 16 + i * 8] = o;
        }
    }

    // ---------- phase 1b: edge aggregation, 2 passes of 32 rows ----------
    {
        int u = t & 3;             // 16B chunk within each 64B window
        int slot = (t >> 2) & 3;   // edge slot (lane bits 2..3)
        int rloc = t >> 4;         // row within pass [0,32)
#pragma unroll 1
        for (int pass = 0; pass < 2; ++pass) {
            int row = pass * 32 + rloc;
            int beg = (row0 + row) * BCAP;
            int num = s_num[row];
            float acc[32] = {};
            float4 A[8], B[8];
            int eA = slot, eB = slot + 4;
            bool hasA = eA < num, hasB = eB < num;
            if (hasA) {
                const float* rp = &X[(size_t)bkt[beg + eA] * F_IN + u * 4];
#pragma unroll
                for (int i = 0; i < 8; ++i) A[i] = *(const float4*)(rp + i * 16);
            }
            if (hasB) {
                const float* rp = &X[(size_t)bkt[beg + eB] * F_IN + u * 4];
#pragma unroll
                for (int i = 0; i < 8; ++i) B[i] = *(const float4*)(rp + i * 16);
            }
#pragma unroll 1
            while (hasA) {
                // consume A (waits A only; B's loads remain outstanding)
#pragma unroll
                for (int i = 0; i < 8; ++i) {
                    acc[i * 4 + 0] += A[i].x;
                    acc[i * 4 + 1] += A[i].y;
                    acc[i * 4 + 2] += A[i].z;
                    acc[i * 4 + 3] += A[i].w;
                }
                eA += 8;
                hasA = eA < num;
                if (hasA) {
                    const float* rp = &X[(size_t)bkt[beg + eA] * F_IN + u * 4];
#pragma unroll
                    for (int i = 0; i < 8; ++i) A[i] = *(const float4*)(rp + i * 16);
                }
                if (hasB) {
#pragma unroll
                    for (int i = 0; i < 8; ++i) {
                        acc[i * 4 + 0] += B[i].x;
                        acc[i * 4 + 1] += B[i].y;
                        acc[i * 4 + 2] += B[i].z;
                        acc[i * 4 + 3] += B[i].w;
                    }
                    eB += 8;
                    hasB = eB < num;
                    if (hasB) {
                        const float* rp = &X[(size_t)bkt[beg + eB] * F_IN + u * 4];
#pragma unroll
                        for (int i = 0; i < 8; ++i) B[i] = *(const float4*)(rp + i * 16);
                    }
                }
            }
            // combine the 4 slots (lane bits 2..3) via butterfly
#pragma unroll
            for (int i = 0; i < 32; ++i) {
                acc[i] += __shfl_xor(acc[i], 4);
                acc[i] += __shfl_xor(acc[i], 8);
            }
            if (slot == 0) {
                float inv = 1.f / (float)((num > 0) ? num : 1);
#pragma unroll
                for (int i = 0; i < 8; ++i) {
                    ushort4 o;
                    o.x = f2bf(acc[i * 4 + 0] * inv);
                    o.y = f2bf(acc[i * 4 + 1] * inv);
                    o.z = f2bf(acc[i * 4 + 2] * inv);
                    o.w = f2bf(acc[i * 4 + 3] * inv);
                    *(ushort4*)&As[row][i * 16 + u * 4] = o;
                }
            }
        }
    }

    // ---------- phase 2: GEMM (Bs-staged, wave tile 32m x 16n) ----------
    int lane = t & 63;
    int w = t >> 6;
    int wm = w >> 2, wn2 = w & 3;  // 2(m) x 4(n) wave grid
    int lr = lane & 15, lj = lane >> 4;
    int bn = t >> 3, bk = (t & 7) * 8;  // B stage map: 64 n-rows x 64 k

    for (int nt = 0; nt < 4; ++nt) {
        f32x4 acc2[2] = {};
        for (int k0 = 0; k0 < 256; k0 += 64) {
            short8 bv = *(const short8*)&Bt[(size_t)(nt * 64 + bn) * 256 + k0 + bk];
            __syncthreads();  // As writes done (1st iter); prior Bs reads done
            *(short8*)&Bs[bn][bk] = bv;
            __syncthreads();
#pragma unroll
            for (int ks = 0; ks < 64; ks += 32) {
                short8 bf = *(const short8*)&Bs[wn2 * 16 + lr][ks + lj * 8];
#pragma unroll
                for (int mi = 0; mi < 2; ++mi) {
                    short8 af = *(const short8*)&As[wm * 32 + mi * 16 + lr][k0 + ks + lj * 8];
                    acc2[mi] = __builtin_amdgcn_mfma_f32_16x16x32_bf16(af, bf, acc2[mi], 0, 0, 0);
                }
            }
        }
        int c = nt * 64 + wn2 * 16 + lr;
        float bi = bias[c];
#pragma unroll
        for (int mi = 0; mi < 2; ++mi) {
#pragma unroll
            for (int j = 0; j < 4; ++j) {
                int r = row0 + wm * 32 + mi * 16 + lj * 4 + j;
                float v = acc2[mi][j] + bi;
                v = fmaxf(v, 0.f);
                C[(size_t)r * HID + c] = f2bf(v);
            }
        }
    }
}

// ------------------------------------------------------------------
// FUSED layer-2: aggregate h (mean) + own-row concat -> LDS -> MFMA GEMM
//   out[64 rows][128] = [mean(h) | h_own] @ Bt1^T + bias (fp32 out)
// 128 blocks x 512 threads. LDS ~76 KB. h is ~46 MB (mostly L3-resident).
// Phase 1b: 8 threads/row, each owns 32 contiguous cols (fully coalesced).
// ------------------------------------------------------------------
__global__ __launch_bounds__(512, 2) void fused2_k(
    const ushort* __restrict__ H, const int* __restrict__ bkt,
    const int* __restrict__ cnt, const ushort* __restrict__ Bt,
    const float* __restrict__ bias, float* __restrict__ out) {
    __shared__ ushort As[64][520];  // [row][mean(0..255) | own h(256..511)], +8 pad
    __shared__ ushort Bs[64][72];
    __shared__ int s_num[64];

    int t = threadIdx.x;
    int row0 = blockIdx.x * 64;
    if (t < 64) s_num[t] = cnt[ND0 + row0 + t];
    __syncthreads();

    // ---------- phase 1a: own h row -> As[row][256..511] ----------
    {
        int row = t >> 3, q = t & 7;
        const ushort* hp = &H[(size_t)(row0 + row) * HID + q * 32];
#pragma unroll
        for (int i = 0; i < 4; ++i)
            *(short8*)&As[row][HID + q * 32 + i * 8] = *(const short8*)(hp + i * 8);
    }

    // ---------- phase 1b: mean over src h rows ----------
    {
        int row = t >> 3, q = t & 7;
        int beg = (ND0 + row0 + row) * BCAP;
        int num = s_num[row];
        float acc[32] = {};
#pragma unroll 1
        for (int e = 0; e < num; ++e) {
            const ushort* rp = &H[(size_t)bkt[beg + e] * HID + q * 32];
#pragma unroll
            for (int i = 0; i < 4; ++i) {
                short8 x = *(const short8*)(rp + i * 8);
#pragma unroll
                for (int j = 0; j < 8; ++j) acc[i * 8 + j] += bf2f((ushort)x[j]);
            }
        }
        float inv = 1.f / (float)((num > 0) ? num : 1);
#pragma unroll
        for (int i = 0; i < 4; ++i) {
            short8 o;
#pragma unroll
            for (int j = 0; j < 8; ++j) o[j] = (short)f2bf(acc[i * 8 + j] * inv);
            *(short8*)&As[row][q * 32 + i * 8] = o;
        }
    }

    // ---------- phase 2: GEMM K=512, NCOLS=128 ----------
    int lane = t & 63;
    int w = t >> 6;
    int wm = w >> 2, wn2 = w & 3;  // 2(m) x 4(n) wave grid
    int lr = lane & 15, lj = lane >> 4;
    int bn = t >> 3, bk = (t & 7) * 8;

    for (int nt = 0; nt < 2; ++nt) {
        f32x4 acc2[2] = {};
        for (int k0 = 0; k0 < 512; k0 += 64) {
            short8 bv = *(const short8*)&Bt[(size_t)(nt * 64 + bn) * 512 + k0 + bk];
            __syncthreads();  // As writes done (1st iter); prior Bs reads done
            *(short8*)&Bs[bn][bk] = bv;
            __syncthreads();
#pragma unroll
            for (int ks = 0; ks < 64; ks += 32) {
                short8 bf = *(const short8*)&Bs[wn2 * 16 + lr][ks + lj * 8];
#pragma unroll
                for (int mi = 0; mi < 2; ++mi) {
                    short8 af = *(const short8*)&As[wm * 32 + mi * 16 + lr][k0 + ks + lj * 8];
                    acc2[mi] = __builtin_amdgcn_mfma_f32_16x16x32_bf16(af, bf, acc2[mi], 0, 0, 0);
                }
            }
        }
        int c = nt * 64 + wn2 * 16 + lr;
        float bi = bias[c];
#pragma unroll
        for (int mi = 0; mi < 2; ++mi) {
#pragma unroll
            for (int j = 0; j < 4; ++j) {
                int r = row0 + wm * 32 + mi * 16 + lj * 4 + j;
                out[(size_t)r * F_OUT + c] = acc2[mi][j] + bi;
            }
        }
    }
}

// ------------------------------------------------------------------
extern "C" void kernel_launch(void* const* d_in, const int* in_sizes, int n_in,
                              void* d_out, int out_size, void* d_ws, size_t ws_size,
                              hipStream_t stream) {
    const float* x_all = (const float*)d_in[0];
    const int* n_id = (const int*)d_in[1];
    const int* esrc0 = (const int*)d_in[2];
    const int* edst0 = (const int*)d_in[3];
    const int* esrc1 = (const int*)d_in[4];
    const int* edst1 = (const int*)d_in[5];
    const float* W_l0 = (const float*)d_in[6];
    const float* b_l0 = (const float*)d_in[7];
    const float* W_r0 = (const float*)d_in[8];
    const float* W_l1 = (const float*)d_in[9];
    const float* b_l1 = (const float*)d_in[10];
    const float* W_r1 = (const float*)d_in[11];

    char* ws = (char*)d_ws;
    size_t off = 0;
    auto alloc = [&](size_t bytes) {
        off = (off + 255) & ~(size_t)255;
        void* p = ws + off;
        off += bytes;
        return p;
    };
    int* cnt = (int*)alloc((size_t)NDT * 4);            // zeroed each launch
    int* bkt = (int*)alloc((size_t)NDT * BCAP * 4);     // 25 MB bucket table
    ushort* h = (ushort*)alloc((size_t)ND0 * HID * 2);
    ushort* Bt0 = (ushort*)alloc((size_t)HID * (2 * F_IN) * 2);
    ushort* Bt1 = (ushort*)alloc((size_t)F_OUT * (2 * HID) * 2);

    hipMemsetAsync(cnt, 0, (size_t)NDT * 4, stream);

    // weight prep + bucket CSR build (single kernel)
    prep_k<<<WT_BLOCKS + (NET + 255) / 256, 256, 0, stream>>>(
        W_l0, W_r0, W_l1, W_r1, Bt0, Bt1, esrc0, edst0, esrc1, edst1, n_id, cnt, bkt);

    // Layer 1 (fused agg + gather + GEMM)
    fused1_k<<<ND0 / 64, 512, 0, stream>>>(x_all, bkt, cnt, n_id, Bt0, b_l0, h);

    // Layer 2 (fused agg + own-row + GEMM)
    fused2_k<<<ND1 / 64, 512, 0, stream>>>(h, bkt, cnt, Bt1, b_l1, (float*)d_out);
}

// Round 14
// 240.711 us; speedup vs baseline: 1.5537x; 1.5537x over previous
//
#include <hip/hip_runtime.h>

// Problem constants (from setup_inputs)
#define ND0 90112
#define ND1 8192
#define NDT (ND0 + ND1)         // 98304 combined dst space
#define NE0 1351680
#define NE1 81920
#define NET (NE0 + NE1)
#define F_IN 128
#define HID 256
#define F_OUT 128
#define BCAP 64                 // per-dst bucket capacity; P(deg>=64) ~ 1e-56
#define WT_BLOCKS 512           // prep_k blocks doing weight transpose

typedef __attribute__((ext_vector_type(8))) short short8;
typedef __attribute__((ext_vector_type(4))) float f32x4;

__device__ inline ushort f2bf(float f) {
    unsigned u = __float_as_uint(f);
    return (ushort)((u + 0x7fffu + ((u >> 16) & 1u)) >> 16);
}
__device__ inline float bf2f(ushort h) {
    return __uint_as_float(((unsigned)h) << 16);
}

// ------------------------------------------------------------------
// prep: weight transpose+convert (blocks [0,512)) + one-kernel bucket
// CSR build (blocks [512, 512+5280)). Row d's srcs: bkt[d*BCAP .. +cnt[d]).
// ------------------------------------------------------------------
__global__ void prep_k(const float* __restrict__ Wl0, const float* __restrict__ Wr0,
                       const float* __restrict__ Wl1, const float* __restrict__ Wr1,
                       ushort* __restrict__ Bt0, ushort* __restrict__ Bt1,
                       const int* __restrict__ esrc0, const int* __restrict__ edst0,
                       const int* __restrict__ esrc1, const int* __restrict__ edst1,
                       const int* __restrict__ nid, int* __restrict__ cnt,
                       int* __restrict__ bkt) {
    if (blockIdx.x < WT_BLOCKS) {
        int idx = blockIdx.x * 256 + threadIdx.x;
        constexpr int N0 = HID * 2 * F_IN;  // 65536
        if (idx < N0) {
            int K2 = 2 * F_IN;
            int n = idx / K2, k = idx - n * K2;
            float v = (k < F_IN) ? Wl0[(size_t)k * HID + n]
                                 : Wr0[(size_t)(k - F_IN) * HID + n];
            Bt0[idx] = f2bf(v);
        } else {
            int j = idx - N0;  // F_OUT * 2 * HID = 65536
            int K2 = 2 * HID;
            int n = j / K2, k = j - n * K2;
            float v = (k < HID) ? Wl1[(size_t)k * F_OUT + n]
                                : Wr1[(size_t)(k - HID) * F_OUT + n];
            Bt1[j] = f2bf(v);
        }
    } else {
        int e = (blockIdx.x - WT_BLOCKS) * 256 + threadIdx.x;
        if (e >= NET) return;
        int d, s;
        if (e < NE0) {
            d = edst0[e];
            s = nid[esrc0[e]];
        } else {
            int e1 = e - NE0;
            d = ND0 + edst1[e1];
            s = esrc1[e1];
        }
        int pos = atomicAdd(&cnt[d], 1);
        if (pos < BCAP) bkt[(size_t)d * BCAP + pos] = s;
    }
}

// ------------------------------------------------------------------
// FUSED layer-1: aggregate (mean) + x_dst gather -> LDS A-tile -> MFMA GEMM
//   h[64 rows][256] = relu([mean | x_dst] @ Bt0^T + bias)
// BM=64: 1408 blocks x 512 threads (8 waves). LDS ~43 KB -> 3 blocks/CU.
// R14 lane map: u8 = t&7 selects the 16B chunk WITHIN a 128B cache line
// (addr = u8*16 + i*128 bytes), so 8 adjacent lanes cover one full aligned
// 128B line per instruction -> 4 line-requests per 512B row (was 8 with the
// 64B/quad map). slot2 = lane bit 3 gives 2 edge slots per row (R4 showed
// slot parallelism is non-binding).
// ------------------------------------------------------------------
__global__ __launch_bounds__(512, 4) void fused1_k(
    const float* __restrict__ X, const int* __restrict__ bkt,
    const int* __restrict__ cnt, const int* __restrict__ nid,
    const ushort* __restrict__ Bt, const float* __restrict__ bias,
    ushort* __restrict__ C) {
    __shared__ ushort As[64][264];  // [row][mean(0..127) | xdst(128..255)], +8 pad
    __shared__ ushort Bs[64][72];
    __shared__ int s_num[64];

    int t = threadIdx.x;
    int row0 = blockIdx.x * 64;

    if (t < 64) s_num[t] = cnt[row0 + t];
    __syncthreads();

    // ---------- phase 1a: x_dst gather (8 threads/row, 16 cols each) ----------
    {
        int row = t >> 3, q = t & 7;
        int gr = nid[row0 + row];
        const float* gp = &X[(size_t)gr * F_IN + q * 16];
#pragma unroll
        for (int i = 0; i < 2; ++i) {
            float4 v0 = *(const float4*)(gp + i * 8);
            float4 v1 = *(const float4*)(gp + i * 8 + 4);
            short8 o;
            o[0] = (short)f2bf(v0.x); o[1] = (short)f2bf(v0.y);
            o[2] = (short)f2bf(v0.z); o[3] = (short)f2bf(v0.w);
            o[4] = (short)f2bf(v1.x); o[5] = (short)f2bf(v1.y);
            o[6] = (short)f2bf(v1.z); o[7] = (short)f2bf(v1.w);
            *(short8*)&As[row][F_IN + q * 16 + i * 8] = o;
        }
    }

    // ---------- phase 1b: edge aggregation, 2 passes of 32 rows ----------
    {
        int u8 = t & 7;            // 16B chunk within each 128B line
        int slot = (t >> 3) & 1;   // edge slot (lane bit 3)
        int rloc = t >> 4;         // row within pass [0,32)
#pragma unroll 1
        for (int pass = 0; pass < 2; ++pass) {
            int row = pass * 32 + rloc;
            int beg = (row0 + row) * BCAP;
            int num = s_num[row];
            float acc[16] = {};
#pragma unroll 1
            for (int e = slot; e < num; e += 2) {
                int r = bkt[beg + e];
                // lane u8 covers bytes u8*16 + i*128 of the 512B row:
                // 8 adjacent lanes -> one full aligned 128B line per instr.
                const float* rp = &X[(size_t)r * F_IN + u8 * 4];
#pragma unroll
                for (int i = 0; i < 4; ++i) {
                    float4 v = *(const float4*)(rp + i * 32);
                    acc[i * 4 + 0] += v.x;
                    acc[i * 4 + 1] += v.y;
                    acc[i * 4 + 2] += v.z;
                    acc[i * 4 + 3] += v.w;
                }
            }
            // combine the 2 slots (lane bit 3) via butterfly
#pragma unroll
            for (int i = 0; i < 16; ++i) acc[i] += __shfl_xor(acc[i], 8);
            if (slot == 0) {
                float inv = 1.f / (float)((num > 0) ? num : 1);
                // lane u8 holds cols {i*32 + u8*4 .. +4}: 4 x 8B stores
#pragma unroll
                for (int i = 0; i < 4; ++i) {
                    ushort4 o;
                    o.x = f2bf(acc[i * 4 + 0] * inv);
                    o.y = f2bf(acc[i * 4 + 1] * inv);
                    o.z = f2bf(acc[i * 4 + 2] * inv);
                    o.w = f2bf(acc[i * 4 + 3] * inv);
                    *(ushort4*)&As[row][i * 32 + u8 * 4] = o;
                }
            }
        }
    }

    // ---------- phase 2: GEMM (Bs-staged, wave tile 32m x 16n) ----------
    int lane = t & 63;
    int w = t >> 6;
    int wm = w >> 2, wn2 = w & 3;  // 2(m) x 4(n) wave grid
    int lr = lane & 15, lj = lane >> 4;
    int bn = t >> 3, bk = (t & 7) * 8;  // B stage map: 64 n-rows x 64 k

    for (int nt = 0; nt < 4; ++nt) {
        f32x4 acc2[2] = {};
        for (int k0 = 0; k0 < 256; k0 += 64) {
            short8 bv = *(const short8*)&Bt[(size_t)(nt * 64 + bn) * 256 + k0 + bk];
            __syncthreads();  // As writes done (1st iter); prior Bs reads done
            *(short8*)&Bs[bn][bk] = bv;
            __syncthreads();
#pragma unroll
            for (int ks = 0; ks < 64; ks += 32) {
                short8 bf = *(const short8*)&Bs[wn2 * 16 + lr][ks + lj * 8];
#pragma unroll
                for (int mi = 0; mi < 2; ++mi) {
                    short8 af = *(const short8*)&As[wm * 32 + mi * 16 + lr][k0 + ks + lj * 8];
                    acc2[mi] = __builtin_amdgcn_mfma_f32_16x16x32_bf16(af, bf, acc2[mi], 0, 0, 0);
                }
            }
        }
        int c = nt * 64 + wn2 * 16 + lr;
        float bi = bias[c];
#pragma unroll
        for (int mi = 0; mi < 2; ++mi) {
#pragma unroll
            for (int j = 0; j < 4; ++j) {
                int r = row0 + wm * 32 + mi * 16 + lj * 4 + j;
                float v = acc2[mi][j] + bi;
                v = fmaxf(v, 0.f);
                C[(size_t)r * HID + c] = f2bf(v);
            }
        }
    }
}

// ------------------------------------------------------------------
// Mean aggregation (layer 2), vectorized 16B/lane, bf16 in.
// ------------------------------------------------------------------
template <int F>
__global__ __launch_bounds__(128) void agg_k(
    const ushort* __restrict__ Xh, const int* __restrict__ bkt,
    const int* __restrict__ cnt, int dofs, ushort* __restrict__ mean) {
    __shared__ float sh[128][8];
    int d = blockIdx.x;
    int t = threadIdx.x;
    int cg = t & 31, slot = t >> 5;
    int beg = (dofs + d) * BCAP;
    int num = cnt[dofs + d];
    float acc[8] = {};
    for (int e = 0; e < num; e += 8) {
        int i0 = e + slot, i1 = e + 4 + slot;
        bool v0 = i0 < num, v1 = i1 < num;
        int r0 = v0 ? bkt[beg + i0] : 0;
        int r1 = v1 ? bkt[beg + i1] : 0;
        if (v0) {
            short8 x = *(const short8*)&Xh[(size_t)r0 * F + cg * 8];
#pragma unroll
            for (int i = 0; i < 8; ++i) acc[i] += bf2f((ushort)x[i]);
        }
        if (v1) {
            short8 x = *(const short8*)&Xh[(size_t)r1 * F + cg * 8];
#pragma unroll
            for (int i = 0; i < 8; ++i) acc[i] += bf2f((ushort)x[i]);
        }
    }
#pragma unroll
    for (int i = 0; i < 8; ++i) sh[t][i] = acc[i];
    __syncthreads();
    if (t < 32) {
        float inv = 1.f / (float)((num > 0) ? num : 1);
        short8 ov;
#pragma unroll
        for (int i = 0; i < 8; ++i) {
            float s = sh[t][i] + sh[t + 32][i] + sh[t + 64][i] + sh[t + 96][i];
            ov[i] = (short)f2bf(s * inv);
        }
        *(short8*)&mean[(size_t)d * F + t * 8] = ov;
    }
}

// ------------------------------------------------------------------
// bf16 MFMA concat-K GEMM (layer 2): C = [A0 | A1] @ Bt^T + bias
// ------------------------------------------------------------------
template <int BM, int KHALF, int NCOLS, bool RELU, bool OUT_BF16>
__global__ __launch_bounds__(256) void mgemm_k(
    const ushort* __restrict__ A0, const ushort* __restrict__ A1,
    const ushort* __restrict__ Bt, const float* __restrict__ bias,
    void* __restrict__ Cv, int M) {
    constexpr int MI = BM / 32;
    constexpr int TPR = 256 / BM;
    constexpr int AV = 64 / TPR / 8;
    __shared__ ushort As[BM][72];
    __shared__ ushort Bs[64][72];

    int t = threadIdx.x;
    int row0 = blockIdx.x * BM;
    int col0 = blockIdx.y * 64;
    int lane = t & 63;
    int w = t >> 6, wm = w >> 1, wn = w & 1;
    int lr = lane & 15;
    int lk = (lane >> 4) * 8;

    int ar = t / TPR, ac = (t % TPR) * (64 / TPR);
    int bn = t >> 2, bc = (t & 3) * 16;

    f32x4 acc[MI][2] = {};

    for (int k0 = 0; k0 < 2 * KHALF; k0 += 64) {
        const ushort* Asrc = (k0 < KHALF) ? A0 : A1;
        int kof = (k0 < KHALF) ? k0 : (k0 - KHALF);
        const ushort* ap = &Asrc[(size_t)(row0 + ar) * KHALF + kof + ac];
        const ushort* bp = &Bt[(size_t)(col0 + bn) * (2 * KHALF) + k0 + bc];
        short8 av[AV];
#pragma unroll
        for (int i = 0; i < AV; ++i) av[i] = *(const short8*)(ap + 8 * i);
        short8 bv0 = *(const short8*)(bp);
        short8 bv1 = *(const short8*)(bp + 8);
        __syncthreads();
#pragma unroll
        for (int i = 0; i < AV; ++i) *(short8*)&As[ar][ac + 8 * i] = av[i];
        *(short8*)&Bs[bn][bc + 0] = bv0;
        *(short8*)&Bs[bn][bc + 8] = bv1;
        __syncthreads();
#pragma unroll
        for (int ks = 0; ks < 64; ks += 32) {
            short8 bf0 = *(const short8*)&Bs[wn * 32 + lr][ks + lk];
            short8 bf1 = *(const short8*)&Bs[wn * 32 + 16 + lr][ks + lk];
#pragma unroll
            for (int mi = 0; mi < MI; ++mi) {
                short8 af = *(const short8*)&As[wm * (BM / 2) + mi * 16 + lr][ks + lk];
                acc[mi][0] = __builtin_amdgcn_mfma_f32_16x16x32_bf16(af, bf0, acc[mi][0], 0, 0, 0);
                acc[mi][1] = __builtin_amdgcn_mfma_f32_16x16x32_bf16(af, bf1, acc[mi][1], 0, 0, 0);
            }
        }
    }

    int orow = row0 + wm * (BM / 2);
    int ocol = col0 + wn * 32;
#pragma unroll
    for (int mi = 0; mi < MI; ++mi) {
#pragma unroll
        for (int ni = 0; ni < 2; ++ni) {
            int c = ocol + ni * 16 + lr;
            float bi = bias[c];
#pragma unroll
            for (int j = 0; j < 4; ++j) {
                int r = orow + mi * 16 + (lane >> 4) * 4 + j;
                float v = acc[mi][ni][j] + bi;
                if (RELU) v = fmaxf(v, 0.f);
                if (OUT_BF16)
                    ((ushort*)Cv)[(size_t)r * NCOLS + c] = f2bf(v);
                else
                    ((float*)Cv)[(size_t)r * NCOLS + c] = v;
            }
        }
    }
}

// ------------------------------------------------------------------
extern "C" void kernel_launch(void* const* d_in, const int* in_sizes, int n_in,
                              void* d_out, int out_size, void* d_ws, size_t ws_size,
                              hipStream_t stream) {
    const float* x_all = (const float*)d_in[0];
    const int* n_id = (const int*)d_in[1];
    const int* esrc0 = (const int*)d_in[2];
    const int* edst0 = (const int*)d_in[3];
    const int* esrc1 = (const int*)d_in[4];
    const int* edst1 = (const int*)d_in[5];
    const float* W_l0 = (const float*)d_in[6];
    const float* b_l0 = (const float*)d_in[7];
    const float* W_r0 = (const float*)d_in[8];
    const float* W_l1 = (const float*)d_in[9];
    const float* b_l1 = (const float*)d_in[10];
    const float* W_r1 = (const float*)d_in[11];

    char* ws = (char*)d_ws;
    size_t off = 0;
    auto alloc = [&](size_t bytes) {
        off = (off + 255) & ~(size_t)255;
        void* p = ws + off;
        off += bytes;
        return p;
    };
    int* cnt = (int*)alloc((size_t)NDT * 4);            // zeroed each launch
    int* bkt = (int*)alloc((size_t)NDT * BCAP * 4);     // 25 MB bucket table
    ushort* h = (ushort*)alloc((size_t)ND0 * HID * 2);
    ushort* mean1 = (ushort*)alloc((size_t)ND1 * HID * 2);
    ushort* Bt0 = (ushort*)alloc((size_t)HID * (2 * F_IN) * 2);
    ushort* Bt1 = (ushort*)alloc((size_t)F_OUT * (2 * HID) * 2);

    hipMemsetAsync(cnt, 0, (size_t)NDT * 4, stream);

    // weight prep + bucket CSR build (single kernel, disjoint block ranges)
    prep_k<<<WT_BLOCKS + (NET + 255) / 256, 256, 0, stream>>>(
        W_l0, W_r0, W_l1, W_r1, Bt0, Bt1, esrc0, edst0, esrc1, edst1, n_id, cnt, bkt);

    // ---------------- Layer 1 (fused agg + gather + GEMM) ----------------
    fused1_k<<<ND0 / 64, 512, 0, stream>>>(x_all, bkt, cnt, n_id, Bt0, b_l0, h);

    // ---------------- Layer 2 ----------------
    agg_k<HID><<<ND1, 128, 0, stream>>>(h, bkt, cnt, ND0, mean1);
    mgemm_k<64, HID, F_OUT, false, false>
        <<<dim3(ND1 / 64, F_OUT / 64), 256, 0, stream>>>(mean1, h, Bt1, b_l1,
                                                         (float*)d_out, ND1);
}